// Round 1
// baseline (331.718 us; speedup 1.0000x reference)
//
#include <hip/hip_runtime.h>
#include <cstdint>
#include <cstddef>

// Problem constants
#define BATCH 8
#define CIN   512
#define COUT  512
#define RES   64
#define HW    4096      // 64*64
#define WDIM  512

typedef short bf16x8 __attribute__((ext_vector_type(8)));
typedef float f32x4  __attribute__((ext_vector_type(4)));

typedef const __attribute__((address_space(1))) void* gas_ptr;
typedef __attribute__((address_space(3))) void*       las_ptr;

__device__ __forceinline__ unsigned short f2bf(float f) {
    unsigned int u = __float_as_uint(f);
    u += 0x7fffu + ((u >> 16) & 1u);   // round-to-nearest-even
    return (unsigned short)(u >> 16);
}

// ---------------------------------------------------------------------------
// Kernel 1: style[b][ci] = sum_wd w[b][wd] * affine_w[ci][wd] + affine_b[ci]
// One wave per output (4096 outputs). Also zeroes the zero-page used by conv.
// ---------------------------------------------------------------------------
__global__ __launch_bounds__(256) void style_kernel(
    const float* __restrict__ w, const float* __restrict__ aw,
    const float* __restrict__ ab, float* __restrict__ style,
    unsigned short* __restrict__ zpage)
{
    if (blockIdx.x == 0 && threadIdx.x < 128) zpage[threadIdx.x] = 0;

    int wv = threadIdx.x >> 6, lane = threadIdx.x & 63;
    int idx = blockIdx.x * 4 + wv;          // 0..4095
    int b = idx >> 9, ci = idx & 511;
    const float* wrow = w + b * WDIM;
    const float* arow = aw + (size_t)ci * WDIM;
    float s = 0.f;
#pragma unroll
    for (int i = 0; i < WDIM / 64; ++i) s += arow[lane + i * 64] * wrow[lane + i * 64];
#pragma unroll
    for (int off = 32; off; off >>= 1) s += __shfl_down(s, off);
    if (lane == 0) style[idx] = s + ab[ci];
}

// ---------------------------------------------------------------------------
// Kernel 2: xs[b][hw][ci] (bf16, NHWC) = bf16(x[b][ci][hw] * style[b][ci])
// 64x64 LDS-tiled transpose, coalesced both sides.
// ---------------------------------------------------------------------------
__global__ __launch_bounds__(256) void modtrans_kernel(
    const float* __restrict__ x, const float* __restrict__ style,
    unsigned short* __restrict__ xs)
{
    __shared__ float tile[64][65];
    int t = threadIdx.x;
    int hw0 = blockIdx.x * 64, ci0 = blockIdx.y * 64, b = blockIdx.z;
    int sub = t >> 6, lane = t & 63;
#pragma unroll
    for (int r = 0; r < 16; ++r) {
        int ci = r * 4 + sub;
        float s = style[b * CIN + ci0 + ci];
        tile[ci][lane] = x[((size_t)(b * CIN + ci0 + ci)) * HW + hw0 + lane] * s;
    }
    __syncthreads();
#pragma unroll
    for (int r = 0; r < 16; ++r) {
        int hw = r * 4 + sub;
        xs[((size_t)b * HW + hw0 + hw) * CIN + ci0 + lane] = f2bf(tile[lane][hw]);
    }
}

// ---------------------------------------------------------------------------
// Kernel 3: wr[tap][co][ci] (bf16) = bf16(weight[co][ci][kh][kw]), tap=kh*3+kw
// One block per co; coalesced global read, coalesced global write.
// ---------------------------------------------------------------------------
__global__ __launch_bounds__(256) void wreorg_kernel(
    const float* __restrict__ wt, unsigned short* __restrict__ wr)
{
    __shared__ float buf[4608];
    int t = threadIdx.x, co = blockIdx.x;
#pragma unroll
    for (int r = 0; r < 18; ++r) buf[r * 256 + t] = wt[(size_t)co * 4608 + r * 256 + t];
    __syncthreads();
#pragma unroll
    for (int r = 0; r < 18; ++r) {
        int idx = r * 256 + t;
        int tap = idx >> 9, ci = idx & 511;
        wr[(size_t)tap * (COUT * CIN) + co * CIN + ci] = f2bf(buf[ci * 9 + tap]);
    }
}

// ---------------------------------------------------------------------------
// Kernel 4: implicit-GEMM conv. C-tile 128(co) x 128(hw: 2 image rows), one
// batch per blockIdx.z. K loop: 9 taps x 16 ci-chunks of 32. m97 structure:
// global_load_lds width-16 staging, 16x16x32 bf16 MFMA, 4 waves x 4x4 frags.
// Padding: OOB staging lanes read a zeroed global page.
// ---------------------------------------------------------------------------
__global__ __launch_bounds__(256) void conv_kernel(
    const unsigned short* __restrict__ xs,   // [8][4096][512] bf16
    const unsigned short* __restrict__ wr,   // [9][512][512]  bf16
    const float* __restrict__ bias,
    const unsigned short* __restrict__ zpage,
    float* __restrict__ y)                   // [8][512][4096] f32
{
    __shared__ __align__(16) unsigned short As[128 * 32];
    __shared__ __align__(16) unsigned short Bs[128 * 32];

    const int t    = threadIdx.x;
    const int co0  = blockIdx.x * 128;
    const int h0   = blockIdx.y * 2;     // two image rows per tile
    const int b    = blockIdx.z;
    const int lane = t & 63;
    const int wv   = t >> 6;
    const int wm   = (wv & 1) * 64;      // wave's M offset in tile
    const int wn   = (wv >> 1) * 64;     // wave's N offset in tile
    const int r16  = lane & 15;
    const int quad = lane >> 4;

    f32x4 acc[4][4];
#pragma unroll
    for (int mi = 0; mi < 4; ++mi)
#pragma unroll
        for (int ni = 0; ni < 4; ++ni)
            acc[mi][ni] = (f32x4){0.f, 0.f, 0.f, 0.f};

#pragma unroll
    for (int kh = 0; kh < 3; ++kh) {
#pragma unroll
        for (int kw = 0; kw < 3; ++kw) {
            const int tap = kh * 3 + kw;
            // per-tap staging pointers (2 16B loads per thread per operand)
            const unsigned short* pA[2];
            const unsigned short* pB[2];
            int sB[2];
#pragma unroll
            for (int L = 0; L < 2; ++L) {
                int lin = L * 256 + t;
                int q = lin >> 2, c8 = (lin & 3) * 8;
                pA[L] = wr + (size_t)tap * (COUT * CIN) + (co0 + q) * CIN + c8;
                int dh = q >> 6, wc = q & 63;
                int hp = h0 + dh + kh - 1, wp = wc + kw - 1;
                bool ok = ((unsigned)hp < 64u) && ((unsigned)wp < 64u);
                pB[L] = ok ? xs + ((size_t)b * HW + hp * 64 + wp) * CIN + c8 : zpage;
                sB[L] = ok ? 32 : 0;
            }
            for (int ch = 0; ch < 16; ++ch) {
#pragma unroll
                for (int L = 0; L < 2; ++L) {
                    int lin = L * 256 + t;
                    __builtin_amdgcn_global_load_lds((gas_ptr)pA[L], (las_ptr)(&As[lin * 8]), 16, 0, 0);
                    __builtin_amdgcn_global_load_lds((gas_ptr)pB[L], (las_ptr)(&Bs[lin * 8]), 16, 0, 0);
                    pA[L] += 32;
                    pB[L] += sB[L];
                }
                __syncthreads();
                bf16x8 af[4], bfv[4];
#pragma unroll
                for (int mi = 0; mi < 4; ++mi)
                    af[mi] = *(const bf16x8*)&As[(wm + mi * 16 + r16) * 32 + quad * 8];
#pragma unroll
                for (int ni = 0; ni < 4; ++ni)
                    bfv[ni] = *(const bf16x8*)&Bs[(wn + ni * 16 + r16) * 32 + quad * 8];
#pragma unroll
                for (int mi = 0; mi < 4; ++mi)
#pragma unroll
                    for (int ni = 0; ni < 4; ++ni)
                        acc[mi][ni] = __builtin_amdgcn_mfma_f32_16x16x32_bf16(
                            af[mi], bfv[ni], acc[mi][ni], 0, 0, 0);
                __syncthreads();
            }
        }
    }

    // Epilogue: C/D layout col(n)=lane&15, row(m)=quad*4+reg
#pragma unroll
    for (int mi = 0; mi < 4; ++mi) {
#pragma unroll
        for (int r = 0; r < 4; ++r) {
            int m = co0 + wm + mi * 16 + quad * 4 + r;
            float bv = bias[m];
            size_t base = ((size_t)b * COUT + m) * HW + h0 * 64;
#pragma unroll
            for (int ni = 0; ni < 4; ++ni) {
                int n = wn + ni * 16 + r16;
                y[base + n] = acc[mi][ni][r] + bv;
            }
        }
    }
}

// ---------------------------------------------------------------------------
extern "C" void kernel_launch(void* const* d_in, const int* in_sizes, int n_in,
                              void* d_out, int out_size, void* d_ws, size_t ws_size,
                              hipStream_t stream)
{
    (void)in_sizes; (void)n_in; (void)out_size; (void)ws_size;
    const float* x    = (const float*)d_in[0];  // [8,512,64,64]
    const float* w    = (const float*)d_in[1];  // [8,512]
    const float* wt   = (const float*)d_in[2];  // [512,512,3,3]
    const float* bias = (const float*)d_in[3];  // [512]
    const float* aw   = (const float*)d_in[4];  // [512,512]
    const float* ab   = (const float*)d_in[5];  // [512]
    float* y = (float*)d_out;                   // [8,512,64,64]

    char* ws = (char*)d_ws;
    float*          style = (float*)ws;                          // 16 KB
    unsigned short* zpage = (unsigned short*)(ws + 16384);       // 256 B
    unsigned short* wr    = (unsigned short*)(ws + 32768);       // 9*512*512*2 = 4.5 MB
    unsigned short* xs    = (unsigned short*)(ws + 4751360);     // 8*4096*512*2 = 32 MB

    style_kernel<<<1024, 256, 0, stream>>>(w, aw, ab, style, zpage);
    modtrans_kernel<<<dim3(64, 8, 8), 256, 0, stream>>>(x, style, xs);
    wreorg_kernel<<<512, 256, 0, stream>>>(wt, wr);
    conv_kernel<<<dim3(4, 32, 8), 256, 0, stream>>>(xs, wr, bias, zpage, y);
}

// Round 2
// 282.404 us; speedup vs baseline: 1.1746x; 1.1746x over previous
//
#include <hip/hip_runtime.h>
#include <cstdint>
#include <cstddef>

// Problem constants
#define BATCH 8
#define CIN   512
#define COUT  512
#define RES   64
#define HW    4096      // 64*64
#define WDIM  512

typedef short bf16x8 __attribute__((ext_vector_type(8)));
typedef float f32x4  __attribute__((ext_vector_type(4)));
typedef unsigned short ushort8 __attribute__((ext_vector_type(8)));

typedef const __attribute__((address_space(1))) void* gas_ptr;
typedef __attribute__((address_space(3))) void*       las_ptr;

__device__ __forceinline__ unsigned short f2bf(float f) {
    unsigned int u = __float_as_uint(f);
    u += 0x7fffu + ((u >> 16) & 1u);   // round-to-nearest-even
    return (unsigned short)(u >> 16);
}

// ---------------------------------------------------------------------------
// Kernel 1: style[b][ci] = sum_wd w[b][wd] * affine_w[ci][wd] + affine_b[ci]
// One wave per output (4096 outputs). Also zeroes the zero-page used by conv.
// ---------------------------------------------------------------------------
__global__ __launch_bounds__(256) void style_kernel(
    const float* __restrict__ w, const float* __restrict__ aw,
    const float* __restrict__ ab, float* __restrict__ style,
    unsigned short* __restrict__ zpage)
{
    if (blockIdx.x == 0 && threadIdx.x < 128) zpage[threadIdx.x] = 0;

    int wv = threadIdx.x >> 6, lane = threadIdx.x & 63;
    int idx = blockIdx.x * 4 + wv;          // 0..4095
    int b = idx >> 9, ci = idx & 511;
    const float* wrow = w + b * WDIM;
    const float* arow = aw + (size_t)ci * WDIM;
    float s = 0.f;
#pragma unroll
    for (int i = 0; i < WDIM / 64; ++i) s += arow[lane + i * 64] * wrow[lane + i * 64];
#pragma unroll
    for (int off = 32; off; off >>= 1) s += __shfl_down(s, off);
    if (lane == 0) style[idx] = s + ab[ci];
}

// ---------------------------------------------------------------------------
// Kernel 2: xs[b][hw][ci] (bf16, NHWC) = bf16(x[b][ci][hw] * style[b][ci])
// 64x64 LDS-tiled transpose; 16B vectorized bf16 stores (8 ci per thread).
// ---------------------------------------------------------------------------
__global__ __launch_bounds__(256) void modtrans_kernel(
    const float* __restrict__ x, const float* __restrict__ style,
    unsigned short* __restrict__ xs)
{
    __shared__ float tile[64][65];
    int t = threadIdx.x;
    int hw0 = blockIdx.x * 64, ci0 = blockIdx.y * 64, b = blockIdx.z;
    int sub = t >> 6, lane = t & 63;
#pragma unroll
    for (int r = 0; r < 16; ++r) {
        int ci = r * 4 + sub;
        float s = style[b * CIN + ci0 + ci];
        tile[ci][lane] = x[((size_t)(b * CIN + ci0 + ci)) * HW + hw0 + lane] * s;
    }
    __syncthreads();
    int ci8 = (t & 7) * 8;
#pragma unroll
    for (int r = 0; r < 2; ++r) {
        int hw = r * 32 + (t >> 3);
        ushort8 v;
#pragma unroll
        for (int j = 0; j < 8; ++j) v[j] = f2bf(tile[ci8 + j][hw]);
        *(ushort8*)&xs[((size_t)b * HW + hw0 + hw) * CIN + ci0 + ci8] = v;
    }
}

// ---------------------------------------------------------------------------
// Kernel 3: wr[tap][co][ci] (bf16) = bf16(weight[co][ci][kh][kw]), tap=kh*3+kw
// ---------------------------------------------------------------------------
__global__ __launch_bounds__(256) void wreorg_kernel(
    const float* __restrict__ wt, unsigned short* __restrict__ wr)
{
    __shared__ float buf[4608];
    int t = threadIdx.x, co = blockIdx.x;
#pragma unroll
    for (int r = 0; r < 18; ++r) buf[r * 256 + t] = wt[(size_t)co * 4608 + r * 256 + t];
    __syncthreads();
#pragma unroll
    for (int r = 0; r < 18; ++r) {
        int idx = r * 256 + t;
        int tap = idx >> 9, ci = idx & 511;
        wr[(size_t)tap * (COUT * CIN) + co * CIN + ci] = f2bf(buf[ci * 9 + tap]);
    }
}

// ---------------------------------------------------------------------------
// Kernel 4: implicit-GEMM conv, restructured K-loop.
// C-tile 128(co) x 128(hw = 2 image rows). Outer kh (3), inner ci-chunk (16).
// Per phase: stage 2 xs rows once into zero-padded Bs[2][66][32] and A for all
// 3 kw taps (As[3][128][32]); all 3 kw taps read the same staged B with a +-1
// column shift. 48 MFMA per barrier pair. LDS 33 KB -> 4 blocks/CU; grid 1024
// fully resident. bid = co*256 + h*8 + b so bid%8 = b: all co-siblings and
// h-neighbours of a batch share an XCD's L2.
// ---------------------------------------------------------------------------
__global__ __launch_bounds__(256) void conv_kernel(
    const unsigned short* __restrict__ xs,   // [8][4096][512] bf16
    const unsigned short* __restrict__ wr,   // [9][512][512]  bf16
    const float* __restrict__ bias,
    const unsigned short* __restrict__ zpage,
    float* __restrict__ y)                   // [8][512][4096] f32
{
    __shared__ __align__(16) unsigned short As[3 * 128 * 32];  // 24 KB
    __shared__ __align__(16) unsigned short Bs[2 * 66 * 32];   // 8.25 KB

    const int t   = threadIdx.x;
    const int bid = blockIdx.x;
    const int co0 = (bid >> 8) * 128;
    const int rem = bid & 255;
    const int h0  = (rem >> 3) * 2;
    const int b   = rem & 7;

    const int lane = t & 63;
    const int wv   = t >> 6;
    const int wm   = (wv & 1) * 64;
    const int wn   = (wv >> 1) * 64;
    const int r16  = lane & 15;
    const int quad = lane >> 4;

    // zero the pad columns (w'=0 and w'=65) of both Bs rows, once
    if (t < 128) {
        int d = t >> 6, c = t & 63;
        int col = (c < 32) ? 0 : 65;
        Bs[(d * 66 + col) * 32 + (c & 31)] = 0;
    }

    f32x4 acc[4][4];
#pragma unroll
    for (int mi = 0; mi < 4; ++mi)
#pragma unroll
        for (int ni = 0; ni < 4; ++ni)
            acc[mi][ni] = (f32x4){0.f, 0.f, 0.f, 0.f};

    for (int kh = 0; kh < 3; ++kh) {
        // A staging pointers: 6 x 16B per thread = As[3 taps][128 co][32 ci]
        const unsigned short* pA[6];
#pragma unroll
        for (int L = 0; L < 6; ++L) {
            int lin = L * 256 + t;                 // 0..1535
            int tap = kh * 3 + (lin >> 9);
            int r9  = lin & 511;
            int q = r9 >> 2, c8 = (r9 & 3) * 8;
            pA[L] = wr + (size_t)tap * (COUT * CIN) + (co0 + q) * CIN + c8;
        }
        // B staging pointers: 2 x 16B per thread = 2 rows x 64 w x 32 ci
        const unsigned short* pB[2];
        int sB[2];
#pragma unroll
        for (int L = 0; L < 2; ++L) {
            int lin = L * 256 + t;                 // 0..511
            int dh = lin >> 8, r8 = lin & 255;
            int wc = r8 >> 2, c8 = (r8 & 3) * 8;
            int hp = h0 + dh + kh - 1;
            bool ok = (unsigned)hp < 64u;
            pB[L] = ok ? xs + ((size_t)b * HW + hp * 64 + wc) * CIN + c8 : zpage;
            sB[L] = ok ? 32 : 0;
        }

        for (int ch = 0; ch < 16; ++ch) {
#pragma unroll
            for (int L = 0; L < 6; ++L) {
                int lin = L * 256 + t;
                __builtin_amdgcn_global_load_lds((gas_ptr)pA[L], (las_ptr)&As[lin * 8], 16, 0, 0);
                pA[L] += 32;
            }
#pragma unroll
            for (int L = 0; L < 2; ++L) {
                int lin = L * 256 + t;
                int dh = lin >> 8, r8 = lin & 255;
                __builtin_amdgcn_global_load_lds((gas_ptr)pB[L],
                    (las_ptr)&Bs[(dh * 66 + 1) * 32 + r8 * 8], 16, 0, 0);
                pB[L] += sB[L];
            }
            __syncthreads();
#pragma unroll
            for (int kw = 0; kw < 3; ++kw) {
                bf16x8 af[4], bfv[4];
#pragma unroll
                for (int mi = 0; mi < 4; ++mi)
                    af[mi] = *(const bf16x8*)&As[(kw * 128 + wm + mi * 16 + r16) * 32 + quad * 8];
#pragma unroll
                for (int ni = 0; ni < 4; ++ni) {
                    int n = wn + ni * 16 + r16;
                    int dh = n >> 6, wc = n & 63;
                    bfv[ni] = *(const bf16x8*)&Bs[(dh * 66 + wc + kw) * 32 + quad * 8];
                }
#pragma unroll
                for (int mi = 0; mi < 4; ++mi)
#pragma unroll
                    for (int ni = 0; ni < 4; ++ni)
                        acc[mi][ni] = __builtin_amdgcn_mfma_f32_16x16x32_bf16(
                            af[mi], bfv[ni], acc[mi][ni], 0, 0, 0);
            }
            __syncthreads();
        }
    }

    // Epilogue: C/D layout col(n)=lane&15, row(m)=quad*4+reg
#pragma unroll
    for (int mi = 0; mi < 4; ++mi) {
#pragma unroll
        for (int r = 0; r < 4; ++r) {
            int m = co0 + wm + mi * 16 + quad * 4 + r;
            float bv = bias[m];
            size_t base = ((size_t)b * COUT + m) * HW + h0 * 64;
#pragma unroll
            for (int ni = 0; ni < 4; ++ni) {
                int n = wn + ni * 16 + r16;
                y[base + n] = acc[mi][ni][r] + bv;
            }
        }
    }
}

// ---------------------------------------------------------------------------
extern "C" void kernel_launch(void* const* d_in, const int* in_sizes, int n_in,
                              void* d_out, int out_size, void* d_ws, size_t ws_size,
                              hipStream_t stream)
{
    (void)in_sizes; (void)n_in; (void)out_size; (void)ws_size;
    const float* x    = (const float*)d_in[0];  // [8,512,64,64]
    const float* w    = (const float*)d_in[1];  // [8,512]
    const float* wt   = (const float*)d_in[2];  // [512,512,3,3]
    const float* bias = (const float*)d_in[3];  // [512]
    const float* aw   = (const float*)d_in[4];  // [512,512]
    const float* ab   = (const float*)d_in[5];  // [512]
    float* y = (float*)d_out;                   // [8,512,64,64]

    char* ws = (char*)d_ws;
    float*          style = (float*)ws;                          // 16 KB
    unsigned short* zpage = (unsigned short*)(ws + 16384);       // 256 B
    unsigned short* wr    = (unsigned short*)(ws + 32768);       // 4.5 MB
    unsigned short* xs    = (unsigned short*)(ws + 4751360);     // 32 MB

    style_kernel<<<1024, 256, 0, stream>>>(w, aw, ab, style, zpage);
    modtrans_kernel<<<dim3(64, 8, 8), 256, 0, stream>>>(x, style, xs);
    wreorg_kernel<<<512, 256, 0, stream>>>(wt, wr);
    conv_kernel<<<1024, 256, 0, stream>>>(xs, wr, bias, zpage, y);
}

// Round 3
// 268.730 us; speedup vs baseline: 1.2344x; 1.0509x over previous
//
#include <hip/hip_runtime.h>
#include <cstdint>
#include <cstddef>

// Problem constants
#define BATCH 8
#define CIN   512
#define COUT  512
#define RES   64
#define HW    4096      // 64*64
#define WDIM  512

typedef short bf16x8 __attribute__((ext_vector_type(8)));
typedef float f32x4  __attribute__((ext_vector_type(4)));
typedef unsigned short ushort8 __attribute__((ext_vector_type(8)));

typedef const __attribute__((address_space(1))) void* gas_ptr;
typedef __attribute__((address_space(3))) void*       las_ptr;

__device__ __forceinline__ unsigned short f2bf(float f) {
    unsigned int u = __float_as_uint(f);
    u += 0x7fffu + ((u >> 16) & 1u);   // round-to-nearest-even
    return (unsigned short)(u >> 16);
}

// ---------------------------------------------------------------------------
// Kernel 1 (fused prep): blocks 0..1023 compute style (+zero zpage);
// blocks 1024..1535 reorganize weights. The two roles are independent.
// style[b][ci] = sum_wd w[b][wd]*affine_w[ci][wd] + affine_b[ci]
// wr[tap][co][ci] = bf16(weight[co][ci][kh][kw]), tap = kh*3+kw
// ---------------------------------------------------------------------------
__global__ __launch_bounds__(256) void prep_kernel(
    const float* __restrict__ w, const float* __restrict__ aw,
    const float* __restrict__ ab, float* __restrict__ style,
    unsigned short* __restrict__ zpage,
    const float* __restrict__ wt, unsigned short* __restrict__ wr)
{
    __shared__ float buf[4608];
    int bid = blockIdx.x;
    int t = threadIdx.x;
    if (bid < 1024) {
        if (bid == 0 && t < 128) zpage[t] = 0;
        int wv = t >> 6, lane = t & 63;
        int idx = bid * 4 + wv;              // 0..4095
        int b = idx >> 9, ci = idx & 511;
        const float* wrow = w + b * WDIM;
        const float* arow = aw + (size_t)ci * WDIM;
        float s = 0.f;
#pragma unroll
        for (int i = 0; i < WDIM / 64; ++i) s += arow[lane + i * 64] * wrow[lane + i * 64];
#pragma unroll
        for (int off = 32; off; off >>= 1) s += __shfl_down(s, off);
        if (lane == 0) style[idx] = s + ab[ci];
    } else {
        int co = bid - 1024;
#pragma unroll
        for (int r = 0; r < 18; ++r) buf[r * 256 + t] = wt[(size_t)co * 4608 + r * 256 + t];
        __syncthreads();
#pragma unroll
        for (int r = 0; r < 18; ++r) {
            int idx = r * 256 + t;
            int tap = idx >> 9, ci = idx & 511;
            wr[(size_t)tap * (COUT * CIN) + co * CIN + ci] = f2bf(buf[ci * 9 + tap]);
        }
    }
}

// ---------------------------------------------------------------------------
// Kernel 2: xs[b][hw][ci] (bf16, NHWC) = bf16(x[b][ci][hw] * style[b][ci])
// 64x64 LDS-tiled transpose; 16B vectorized bf16 stores.
// ---------------------------------------------------------------------------
__global__ __launch_bounds__(256) void modtrans_kernel(
    const float* __restrict__ x, const float* __restrict__ style,
    unsigned short* __restrict__ xs)
{
    __shared__ float tile[64][65];
    int t = threadIdx.x;
    int hw0 = blockIdx.x * 64, ci0 = blockIdx.y * 64, b = blockIdx.z;
    int sub = t >> 6, lane = t & 63;
#pragma unroll
    for (int r = 0; r < 16; ++r) {
        int ci = r * 4 + sub;
        float s = style[b * CIN + ci0 + ci];
        tile[ci][lane] = x[((size_t)(b * CIN + ci0 + ci)) * HW + hw0 + lane] * s;
    }
    __syncthreads();
    int ci8 = (t & 7) * 8;
#pragma unroll
    for (int r = 0; r < 2; ++r) {
        int hw = r * 32 + (t >> 3);
        ushort8 v;
#pragma unroll
        for (int j = 0; j < 8; ++j) v[j] = f2bf(tile[ci8 + j][hw]);
        *(ushort8*)&xs[((size_t)b * HW + hw0 + hw) * CIN + ci0 + ci8] = v;
    }
}

// ---------------------------------------------------------------------------
// Kernel 3: implicit-GEMM conv.
// C-tile 128(co) x 128(hw = 2 image rows). Outer kh (3), inner ci-chunk (16).
// Per phase: stage 2 xs rows into zero-padded Bs[2][66][32] and A for all 3
// kw taps (As[3][128][32]); the 3 kw taps reuse the staged B with a column
// shift. 48 MFMA per barrier pair; LDS 33 KB -> 4 blocks/CU, grid 1024 fully
// resident; bid%8 = batch so co-siblings share an XCD's L2.
//
// Bank-conflict swizzle: logical 16B chunk j of LDS row r lives at physical
// slot j ^ ((r>>1)&3). Staging permutes the per-lane GLOBAL source address
// (LDS dest must stay base+lane*16); fragment reads apply the same xor.
// Turns the 8-way row-stride-64B conflict into free 2-way.
// ---------------------------------------------------------------------------
__global__ __launch_bounds__(256) void conv_kernel(
    const unsigned short* __restrict__ xs,   // [8][4096][512] bf16
    const unsigned short* __restrict__ wr,   // [9][512][512]  bf16
    const float* __restrict__ bias,
    const unsigned short* __restrict__ zpage,
    float* __restrict__ y)                   // [8][512][4096] f32
{
    __shared__ __align__(16) unsigned short As[3 * 128 * 32];  // 24 KB
    __shared__ __align__(16) unsigned short Bs[2 * 66 * 32];   // 8.25 KB

    const int t   = threadIdx.x;
    const int bid = blockIdx.x;
    const int co0 = (bid >> 8) * 128;
    const int rem = bid & 255;
    const int h0  = (rem >> 3) * 2;
    const int b   = rem & 7;

    const int lane = t & 63;
    const int wv   = t >> 6;
    const int wm   = (wv & 1) * 64;
    const int wn   = (wv >> 1) * 64;
    const int r16  = lane & 15;
    const int quad = lane >> 4;

    // zero the pad columns (w'=0 and w'=65) of both Bs rows (swizzle-invariant)
    if (t < 128) {
        int d = t >> 6, c = t & 63;
        int col = (c < 32) ? 0 : 65;
        Bs[(d * 66 + col) * 32 + (c & 31)] = 0;
    }

    f32x4 acc[4][4];
#pragma unroll
    for (int mi = 0; mi < 4; ++mi)
#pragma unroll
        for (int ni = 0; ni < 4; ++ni)
            acc[mi][ni] = (f32x4){0.f, 0.f, 0.f, 0.f};

    for (int kh = 0; kh < 3; ++kh) {
        // A staging: 6 x 16B per thread = As[3 taps][128 co][32 ci], swizzled
        const unsigned short* pA[6];
#pragma unroll
        for (int L = 0; L < 6; ++L) {
            int lin = L * 256 + t;                 // 0..1535; phys row = lin>>2
            int tap = kh * 3 + (lin >> 9);
            int q   = (lin >> 2) & 127;
            int c8  = ((lin & 3) ^ ((lin >> 3) & 3)) * 8;   // swizzled source chunk
            pA[L] = wr + (size_t)tap * (COUT * CIN) + (co0 + q) * CIN + c8;
        }
        // B staging: 2 x 16B per thread = 2 rows x 64 w x 32 ci, swizzled
        const unsigned short* pB[2];
        int sB[2];
#pragma unroll
        for (int L = 0; L < 2; ++L) {
            int lin = L * 256 + t;                 // 0..511
            int dh = lin >> 8, r8 = lin & 255;
            int wc = r8 >> 2;
            int rowp = dh * 66 + 1 + wc;           // physical LDS row
            int c8 = ((r8 & 3) ^ ((rowp >> 1) & 3)) * 8;
            int hp = h0 + dh + kh - 1;
            bool ok = (unsigned)hp < 64u;
            pB[L] = ok ? xs + ((size_t)b * HW + hp * 64 + wc) * CIN + c8 : zpage;
            sB[L] = ok ? 32 : 0;
        }

        for (int ch = 0; ch < 16; ++ch) {
#pragma unroll
            for (int L = 0; L < 6; ++L) {
                int lin = L * 256 + t;
                __builtin_amdgcn_global_load_lds((gas_ptr)pA[L], (las_ptr)&As[lin * 8], 16, 0, 0);
                pA[L] += 32;
            }
#pragma unroll
            for (int L = 0; L < 2; ++L) {
                int lin = L * 256 + t;
                int dh = lin >> 8, r8 = lin & 255;
                __builtin_amdgcn_global_load_lds((gas_ptr)pB[L],
                    (las_ptr)&Bs[(dh * 66 + 1) * 32 + r8 * 8], 16, 0, 0);
                pB[L] += sB[L];
            }
            __syncthreads();
#pragma unroll
            for (int kw = 0; kw < 3; ++kw) {
                bf16x8 af[4], bfv[4];
#pragma unroll
                for (int mi = 0; mi < 4; ++mi) {
                    int row = kw * 128 + wm + mi * 16 + r16;
                    int ck  = quad ^ ((row >> 1) & 3);
                    af[mi] = *(const bf16x8*)&As[row * 32 + ck * 8];
                }
#pragma unroll
                for (int ni = 0; ni < 4; ++ni) {
                    int n = wn + ni * 16 + r16;
                    int dh = n >> 6, wc = n & 63;
                    int row = dh * 66 + wc + kw;
                    int ck  = quad ^ ((row >> 1) & 3);
                    bfv[ni] = *(const bf16x8*)&Bs[row * 32 + ck * 8];
                }
#pragma unroll
                for (int mi = 0; mi < 4; ++mi)
#pragma unroll
                    for (int ni = 0; ni < 4; ++ni)
                        acc[mi][ni] = __builtin_amdgcn_mfma_f32_16x16x32_bf16(
                            af[mi], bfv[ni], acc[mi][ni], 0, 0, 0);
            }
            __syncthreads();
        }
    }

    // Epilogue: C/D layout col(n)=lane&15, row(m)=quad*4+reg
#pragma unroll
    for (int mi = 0; mi < 4; ++mi) {
#pragma unroll
        for (int r = 0; r < 4; ++r) {
            int m = co0 + wm + mi * 16 + quad * 4 + r;
            float bv = bias[m];
            size_t base = ((size_t)b * COUT + m) * HW + h0 * 64;
#pragma unroll
            for (int ni = 0; ni < 4; ++ni) {
                int n = wn + ni * 16 + r16;
                y[base + n] = acc[mi][ni][r] + bv;
            }
        }
    }
}

// ---------------------------------------------------------------------------
extern "C" void kernel_launch(void* const* d_in, const int* in_sizes, int n_in,
                              void* d_out, int out_size, void* d_ws, size_t ws_size,
                              hipStream_t stream)
{
    (void)in_sizes; (void)n_in; (void)out_size; (void)ws_size;
    const float* x    = (const float*)d_in[0];  // [8,512,64,64]
    const float* w    = (const float*)d_in[1];  // [8,512]
    const float* wt   = (const float*)d_in[2];  // [512,512,3,3]
    const float* bias = (const float*)d_in[3];  // [512]
    const float* aw   = (const float*)d_in[4];  // [512,512]
    const float* ab   = (const float*)d_in[5];  // [512]
    float* y = (float*)d_out;                   // [8,512,64,64]

    char* ws = (char*)d_ws;
    float*          style = (float*)ws;                          // 16 KB
    unsigned short* zpage = (unsigned short*)(ws + 16384);       // 256 B
    unsigned short* wr    = (unsigned short*)(ws + 32768);       // 4.5 MB
    unsigned short* xs    = (unsigned short*)(ws + 4751360);     // 32 MB

    prep_kernel<<<1536, 256, 0, stream>>>(w, aw, ab, style, zpage, wt, wr);
    modtrans_kernel<<<dim3(64, 8, 8), 256, 0, stream>>>(x, style, xs);
    conv_kernel<<<1024, 256, 0, stream>>>(xs, wr, bias, zpage, y);
}